// Round 2
// baseline (307.592 us; speedup 1.0000x reference)
//
#include <hip/hip_runtime.h>
#include <stdint.h>
#include <stddef.h>

// ---------------------------------------------------------------------------
// MultiHeadAttentionBlock: B=4, C=2048, D=1024, H=8, K=64, V=128
//
// Derivation of the raw reshapes (verified by index algebra):
//   q_{b,g}[r][k]  = Pq[b*2048 + g*256 + r/8][(r%8)*64 + k]   -> contiguous [2048,64]
//   v_{b,h}[c][d]  = Pv[...] contiguous [2048,128]
//   out[b, c, h, d] = sum_c2 att_{b, g=c/256}[r=(c%256)*8+h][c2] * v_{b,h}[c2][d]
//   att_{bg}[r][c2] = exp(s[r][c2]/8) / sum_r' exp(s[r'][c2]/8)   (softmax over r!)
// Two passes: pass1 -> rden[bg][c2] = 1/colsum, pass2 recomputes S and does P@V.
// All GEMMs via mfma_f32_16x16x32_bf16 (fp32 accum). LDS pitch 72 everywhere
// (16B-aligned ds_read_b128, conflict-free 4(r+q) bank pattern).
// R1 fix: vs staging tile in k_pass2 is 128x64 = 8192 elems -> needs p<4
// (was p<2, leaving d in [64,128) uninitialized -> absmax 0.31).
// ---------------------------------------------------------------------------

typedef short     bf8v  __attribute__((ext_vector_type(8)));   // 8 x bf16 (A/B frag)
typedef float     f4v   __attribute__((ext_vector_type(4)));   // 4 x f32 (C/D frag)
typedef unsigned short u16x4 __attribute__((ext_vector_type(4)));
typedef unsigned short u16x8 __attribute__((ext_vector_type(8)));

__device__ __forceinline__ unsigned short f2bf(float f) {  // RNE f32->bf16
    union { float f; uint32_t u; } v; v.f = f;
    return (unsigned short)((v.u + 0x7fffu + ((v.u >> 16) & 1u)) >> 16);
}

#define MFMA16(A, B, C) __builtin_amdgcn_mfma_f32_16x16x32_bf16((A), (B), (C), 0, 0, 0)

// -------------------- fp32 -> bf16 elementwise convert ----------------------
__global__ __launch_bounds__(256) void k_cvt(const float* __restrict__ in,
                                             unsigned short* __restrict__ out, int n4) {
    int i = blockIdx.x * 256 + threadIdx.x;
    if (i >= n4) return;
    f4v v = *(const f4v*)(in + (size_t)i * 4);
    u16x4 o;
    o[0] = f2bf(v[0]); o[1] = f2bf(v[1]); o[2] = f2bf(v[2]); o[3] = f2bf(v[3]);
    *(u16x4*)(out + (size_t)i * 4) = o;
}

// ------------- fp32 [1024][N] -> bf16 transposed [N][1024] ------------------
__global__ __launch_bounds__(256) void k_cvtT(const float* __restrict__ in,
                                              unsigned short* __restrict__ outT, int Ncols) {
    __shared__ unsigned short t[64][68];
    const int tid = threadIdx.x;
    const int tr = tid >> 4, tc4 = (tid & 15) * 4;
    const int rb = blockIdx.y * 64, cb = blockIdx.x * 64;
#pragma unroll
    for (int p = 0; p < 4; ++p) {
        int r = tr + p * 16;
        f4v v = *(const f4v*)(in + (size_t)(rb + r) * Ncols + cb + tc4);
        t[r][tc4 + 0] = f2bf(v[0]); t[r][tc4 + 1] = f2bf(v[1]);
        t[r][tc4 + 2] = f2bf(v[2]); t[r][tc4 + 3] = f2bf(v[3]);
    }
    __syncthreads();
#pragma unroll
    for (int p = 0; p < 4; ++p) {
        int r = tr + p * 16;               // output row = input col cb + r
        u16x4 o;
        o[0] = t[tc4 + 0][r]; o[1] = t[tc4 + 1][r];
        o[2] = t[tc4 + 2][r]; o[3] = t[tc4 + 3][r];
        *(u16x4*)(outT + (size_t)(cb + r) * 1024 + rb + tc4) = o;
    }
}

// -------- bf16 transpose [2048][128] -> [128][2048], 32 batches (b,h) -------
__global__ __launch_bounds__(256) void k_T(const unsigned short* __restrict__ in,
                                           unsigned short* __restrict__ out) {
    __shared__ unsigned short t[64][68];
    const int tid = threadIdx.x;
    const int tr = tid >> 4, tc4 = (tid & 15) * 4;
    const int rb = blockIdx.y * 64, cb = blockIdx.x * 64;
    const unsigned short* ib = in  + (size_t)blockIdx.z * 262144;
    unsigned short*       ob = out + (size_t)blockIdx.z * 262144;
#pragma unroll
    for (int p = 0; p < 4; ++p) {
        int r = tr + p * 16;
        u16x4 v = *(const u16x4*)(ib + (size_t)(rb + r) * 128 + cb + tc4);
        t[r][tc4 + 0] = v[0]; t[r][tc4 + 1] = v[1];
        t[r][tc4 + 2] = v[2]; t[r][tc4 + 3] = v[3];
    }
    __syncthreads();
#pragma unroll
    for (int p = 0; p < 4; ++p) {
        int r = tr + p * 16;
        u16x4 o;
        o[0] = t[tc4 + 0][r]; o[1] = t[tc4 + 1][r];
        o[2] = t[tc4 + 2][r]; o[3] = t[tc4 + 3][r];
        *(u16x4*)(ob + (size_t)(cb + r) * 2048 + rb + tc4) = o;
    }
}

// ----------- projection GEMM: C[8192][N] = Xb[8192][1024] @ W ---------------
// Wt = [N][1024] (pre-transposed). Computed as C^T so 4 regs = 4 consecutive cols.
__global__ __launch_bounds__(256, 2) void k_gemm(const unsigned short* __restrict__ X,
                                                 const unsigned short* __restrict__ Wt,
                                                 unsigned short* __restrict__ Cg, int N) {
    __shared__ __align__(16) unsigned short xs[128][72];
    __shared__ __align__(16) unsigned short wls[128][72];
    const int tid = threadIdx.x;
    const int lane = tid & 63, w = tid >> 6;
    const int lc = lane & 15, quad = lane >> 4;
    const int rowb = blockIdx.x * 128, colb = blockIdx.y * 128;

    f4v acc[2][8];
#pragma unroll
    for (int mt = 0; mt < 2; ++mt)
#pragma unroll
        for (int nt = 0; nt < 8; ++nt) acc[mt][nt] = f4v{0.f, 0.f, 0.f, 0.f};

    for (int k0 = 0; k0 < 1024; k0 += 64) {
#pragma unroll
        for (int p = 0; p < 4; ++p) {
            int v = tid + p * 256;
            int r = v >> 3, s = (v & 7) * 8;
            *(u16x8*)(&xs[r][s])  = *(const u16x8*)(X  + (size_t)(rowb + r) * 1024 + k0 + s);
            *(u16x8*)(&wls[r][s]) = *(const u16x8*)(Wt + (size_t)(colb + r) * 1024 + k0 + s);
        }
        __syncthreads();
#pragma unroll
        for (int ks = 0; ks < 2; ++ks) {
            int kk = ks * 32 + quad * 8;
            bf8v bx[8];
#pragma unroll
            for (int nt = 0; nt < 8; ++nt) bx[nt] = *(const bf8v*)(&xs[nt * 16 + lc][kk]);
#pragma unroll
            for (int mt = 0; mt < 2; ++mt) {
                bf8v a = *(const bf8v*)(&wls[w * 32 + mt * 16 + lc][kk]);
#pragma unroll
                for (int nt = 0; nt < 8; ++nt) acc[mt][nt] = MFMA16(a, bx[nt], acc[mt][nt]);
            }
        }
        __syncthreads();
    }
    // D (C^T): row = C-col = colb + w*32 + mt*16 + quad*4 + reg ; col = C-row = rowb + nt*16 + lc
#pragma unroll
    for (int mt = 0; mt < 2; ++mt)
#pragma unroll
        for (int nt = 0; nt < 8; ++nt) {
            int crow = rowb + nt * 16 + lc;
            int ccol = colb + w * 32 + mt * 16 + quad * 4;
            u16x4 o;
            o[0] = f2bf(acc[mt][nt][0]); o[1] = f2bf(acc[mt][nt][1]);
            o[2] = f2bf(acc[mt][nt][2]); o[3] = f2bf(acc[mt][nt][3]);
            *(u16x4*)(Cg + (size_t)crow * N + ccol) = o;
        }
}

// --------- pass 1: rden[bg][c2] = 1 / sum_r exp(q_r . k_c2 / 8) -------------
__global__ __launch_bounds__(256, 2) void k_pass1(const unsigned short* __restrict__ Pq,
                                                  const unsigned short* __restrict__ Pk,
                                                  float* __restrict__ rden) {
    __shared__ __align__(16) unsigned short qs[128][72];
    __shared__ __align__(16) unsigned short kss[128][72];
    __shared__ float dsum[4][128];
    const int tid = threadIdx.x;
    const int lane = tid & 63, w = tid >> 6;
    const int lc = lane & 15, quad = lane >> 4;
    const int c2b = blockIdx.x * 128;
    const int bg  = blockIdx.y;
    const unsigned short* qbase = Pq + (size_t)bg * 131072;
    const unsigned short* kbase = Pk + (size_t)bg * 131072 + (size_t)c2b * 64;

#pragma unroll
    for (int p = 0; p < 4; ++p) {      // k tile: 128 rows x 64, contiguous
        int v = tid + p * 256;
        int r = v >> 3, s = (v & 7) * 8;
        *(u16x8*)(&kss[r][s]) = *(const u16x8*)(kbase + (size_t)v * 8);
    }

    float csum[8];
#pragma unroll
    for (int nt = 0; nt < 8; ++nt) csum[nt] = 0.f;

    for (int it = 0; it < 16; ++it) {
        __syncthreads();
        const unsigned short* qit = qbase + (size_t)it * 8192;
#pragma unroll
        for (int p = 0; p < 4; ++p) {
            int v = tid + p * 256;
            int r = v >> 3, s = (v & 7) * 8;
            *(u16x8*)(&qs[r][s]) = *(const u16x8*)(qit + (size_t)v * 8);
        }
        __syncthreads();

        f4v sc[2][8];
#pragma unroll
        for (int mt = 0; mt < 2; ++mt)
#pragma unroll
            for (int nt = 0; nt < 8; ++nt) sc[mt][nt] = f4v{0.f, 0.f, 0.f, 0.f};
#pragma unroll
        for (int ks = 0; ks < 2; ++ks) {
            int kk = ks * 32 + quad * 8;
            bf8v bk[8];
#pragma unroll
            for (int nt = 0; nt < 8; ++nt) bk[nt] = *(const bf8v*)(&kss[nt * 16 + lc][kk]);
#pragma unroll
            for (int mt = 0; mt < 2; ++mt) {
                bf8v a = *(const bf8v*)(&qs[w * 32 + mt * 16 + lc][kk]);
#pragma unroll
                for (int nt = 0; nt < 8; ++nt) sc[mt][nt] = MFMA16(a, bk[nt], sc[mt][nt]);
            }
        }
#pragma unroll
        for (int mt = 0; mt < 2; ++mt)
#pragma unroll
            for (int nt = 0; nt < 8; ++nt)
#pragma unroll
                for (int r = 0; r < 4; ++r)
                    csum[nt] += __expf(sc[mt][nt][r] * 0.125f);
    }

#pragma unroll
    for (int nt = 0; nt < 8; ++nt) {   // reduce across quads (rows live in regs+quads)
        float v = csum[nt];
        v += __shfl_xor(v, 16, 64);
        v += __shfl_xor(v, 32, 64);
        if (quad == 0) dsum[w][nt * 16 + lc] = v;
    }
    __syncthreads();
    if (tid < 128) {
        float tot = dsum[0][tid] + dsum[1][tid] + dsum[2][tid] + dsum[3][tid];
        rden[(size_t)bg * 2048 + c2b + tid] = 1.0f / tot;
    }
}

// --------- pass 2: out[b, g*256+j, h, :] = P_{bg}[j*8+h, :] @ v_{b,h} -------
__global__ __launch_bounds__(256, 2) void k_pass2(const unsigned short* __restrict__ Pq,
                                                  const unsigned short* __restrict__ Pk,
                                                  const unsigned short* __restrict__ Vt,
                                                  const float* __restrict__ rden,
                                                  float* __restrict__ out) {
    __shared__ __align__(16) unsigned short qs[128][72];   // q_sub rows (stride-8 gather)
    __shared__ __align__(16) unsigned short kss[64][72];   // k chunk [c2=64][64]
    __shared__ __align__(16) unsigned short vs[128][72];   // v^T chunk [d=128][c2=64]
    __shared__ __align__(16) unsigned short ps[128][72];   // P chunk [r=128][c2=64]
    __shared__ __align__(16) float rd[64];
    const int tid = threadIdx.x;
    const int lane = tid & 63, w = tid >> 6;
    const int lc = lane & 15, quad = lane >> 4;
    const int jt = blockIdx.x, h = blockIdx.y, bg = blockIdx.z;
    const int b = bg >> 3, g = bg & 7;

    const unsigned short* qbase = Pq + (size_t)bg * 131072;
    const unsigned short* kbase = Pk + (size_t)bg * 131072;
    const unsigned short* vbase = Vt + (size_t)(b * 8 + h) * 262144;
    const float* rdb = rden + (size_t)bg * 2048;

#pragma unroll
    for (int p = 0; p < 4; ++p) {      // q_sub: row i <- global q row (jt*128+i)*8 + h
        int v = tid + p * 256;
        int i = v >> 3, s = (v & 7) * 8;
        *(u16x8*)(&qs[i][s]) =
            *(const u16x8*)(qbase + (size_t)((jt * 128 + i) * 8 + h) * 64 + s);
    }

    f4v acc[2][8];
#pragma unroll
    for (int mt = 0; mt < 2; ++mt)
#pragma unroll
        for (int nt = 0; nt < 8; ++nt) acc[mt][nt] = f4v{0.f, 0.f, 0.f, 0.f};

    for (int cc = 0; cc < 32; ++cc) {
        const int c2b = cc * 64;
        __syncthreads();               // protect kss/vs/ps/rd from previous iter readers
#pragma unroll
        for (int p = 0; p < 2; ++p) {  // k chunk: 64x64 contiguous
            int v = tid + p * 256;
            int r = v >> 3, s = (v & 7) * 8;
            *(u16x8*)(&kss[r][s]) = *(const u16x8*)(kbase + (size_t)c2b * 64 + v * 8);
        }
#pragma unroll
        for (int p = 0; p < 4; ++p) {  // v^T chunk: 128 rows x 64 cols of Vt (8192 elems)
            int v = tid + p * 256;
            int d = v >> 3, s = (v & 7) * 8;
            *(u16x8*)(&vs[d][s]) = *(const u16x8*)(vbase + (size_t)d * 2048 + c2b + s);
        }
        if (tid < 64) rd[tid] = rdb[c2b + tid];
        __syncthreads();

        // S^T stage: D[m=c2][n=r], A=k chunk, B=q_sub. Wave w owns r in [w*32, w*32+32).
        f4v sc[4][2];
#pragma unroll
        for (int mt = 0; mt < 4; ++mt)
#pragma unroll
            for (int nt = 0; nt < 2; ++nt) sc[mt][nt] = f4v{0.f, 0.f, 0.f, 0.f};
#pragma unroll
        for (int ks = 0; ks < 2; ++ks) {
            int kk = ks * 32 + quad * 8;
            bf8v bq[2];
#pragma unroll
            for (int nt = 0; nt < 2; ++nt)
                bq[nt] = *(const bf8v*)(&qs[w * 32 + nt * 16 + lc][kk]);
#pragma unroll
            for (int mt = 0; mt < 4; ++mt) {
                bf8v a = *(const bf8v*)(&kss[mt * 16 + lc][kk]);
#pragma unroll
                for (int nt = 0; nt < 2; ++nt) sc[mt][nt] = MFMA16(a, bq[nt], sc[mt][nt]);
            }
        }
        // P = exp(S/8)*rden, packed b64 writes: 4 regs = 4 consecutive c2
#pragma unroll
        for (int mt = 0; mt < 4; ++mt) {
            f4v rr = *(const f4v*)(&rd[mt * 16 + quad * 4]);
#pragma unroll
            for (int nt = 0; nt < 2; ++nt) {
                u16x4 pw;
#pragma unroll
                for (int r = 0; r < 4; ++r)
                    pw[r] = f2bf(__expf(sc[mt][nt][r] * 0.125f) * rr[r]);
                *(u16x4*)(&ps[w * 32 + nt * 16 + lc][mt * 16 + quad * 4]) = pw;
            }
        }
        __syncthreads();

        // PV stage: Out^T[d][r] += v^T[d][c2] @ P^T[c2][r]. Wave w owns d in [w*32, +32).
#pragma unroll
        for (int ks = 0; ks < 2; ++ks) {
            int kk = ks * 32 + quad * 8;
            bf8v bp[8];
#pragma unroll
            for (int nt = 0; nt < 8; ++nt) bp[nt] = *(const bf8v*)(&ps[nt * 16 + lc][kk]);
#pragma unroll
            for (int mt = 0; mt < 2; ++mt) {
                bf8v a = *(const bf8v*)(&vs[w * 32 + mt * 16 + lc][kk]);
#pragma unroll
                for (int nt = 0; nt < 8; ++nt) acc[mt][nt] = MFMA16(a, bp[nt], acc[mt][nt]);
            }
        }
    }

    // epilogue: lane tile (mt,nt): d = w*32+mt*16+quad*4+reg (4 consecutive), r = nt*16+lc
    float* ob = out + (size_t)(b * 2048 + g * 256 + jt * 128) * 1024 + h * 128;
#pragma unroll
    for (int mt = 0; mt < 2; ++mt)
#pragma unroll
        for (int nt = 0; nt < 8; ++nt) {
            int r = nt * 16 + lc;
            int d = w * 32 + mt * 16 + quad * 4;
            *(f4v*)(ob + (size_t)r * 1024 + d) = acc[mt][nt];
        }
}

// ---------------------------------------------------------------------------
extern "C" void kernel_launch(void* const* d_in, const int* in_sizes, int n_in,
                              void* d_out, int out_size, void* d_ws, size_t ws_size,
                              hipStream_t stream) {
    const float* x  = (const float*)d_in[0];   // [4][2048][1024]
    const float* Mq = (const float*)d_in[1];   // [1024][512]
    const float* Mk = (const float*)d_in[2];   // [1024][512]
    const float* Mv = (const float*)d_in[3];   // [1024][1024]
    float* out = (float*)d_out;                // [4][2048][1024]

    char* base = (char*)d_ws;
    unsigned short* xb  = (unsigned short*)base;  base += 16777216;  // x bf16
    unsigned short* wqt = (unsigned short*)base;  base += 1048576;   // Mq^T bf16 [512][1024]
    unsigned short* wkt = (unsigned short*)base;  base += 1048576;
    unsigned short* wvt = (unsigned short*)base;  base += 2097152;   // Mv^T [1024][1024]
    unsigned short* pq  = (unsigned short*)base;  base += 8388608;   // [4*2048][512]
    unsigned short* pk  = (unsigned short*)base;  base += 8388608;
    unsigned short* pv  = (unsigned short*)base;  base += 16777216;  // [4*2048][1024]
    unsigned short* vt  = (unsigned short*)base;  base += 16777216;  // [32][128][2048]
    float* rden = (float*)base;                   base += 262144;    // [32][2048]

    k_cvt<<<8192, 256, 0, stream>>>(x, xb, 2097152);
    k_cvtT<<<dim3(8, 16), 256, 0, stream>>>(Mq, wqt, 512);
    k_cvtT<<<dim3(8, 16), 256, 0, stream>>>(Mk, wkt, 512);
    k_cvtT<<<dim3(16, 16), 256, 0, stream>>>(Mv, wvt, 1024);
    k_gemm<<<dim3(64, 4), 256, 0, stream>>>(xb, wqt, pq, 512);
    k_gemm<<<dim3(64, 4), 256, 0, stream>>>(xb, wkt, pk, 512);
    k_gemm<<<dim3(64, 8), 256, 0, stream>>>(xb, wvt, pv, 1024);
    k_T<<<dim3(2, 32, 32), 256, 0, stream>>>(pv, vt);
    k_pass1<<<dim3(16, 32), 256, 0, stream>>>(pq, pk, rden);
    k_pass2<<<dim3(2, 8, 32), 256, 0, stream>>>(pq, pk, vt, rden, out);
}